// Round 1
// baseline (19790.678 us; speedup 1.0000x reference)
//
#include <hip/hip_runtime.h>
#include <cstdint>
#include <cstddef>

// LSTM: B=64, T=1024, I=256, H=512. PyTorch gate order i,f,g,o.
// Persistent cooperative kernel: 256 WGs = 8 batch-groups x 32 hidden-groups.
// WG (bg,hg): batches bg*8..bg*8+7, hidden units hg*16..hg*16+15
//   -> 64 rows of combined W = [w_ih | w_hh] (K = 256+512 = 768), bf16 in LDS.
// Sync: only within a batch-group (32 WGs) via monotone flags + double-buffered h.

#define NBATCH 64
#define TSTEPS 1024
#define IDIM   256
#define HDIM   512
#define KDIM   768      // IDIM + HDIM
#define WSTR   776      // bf16 row stride (16B-aligned, bank-spread)
#define ASTR   772      // fp32 act row stride (16B-aligned, bank-spread)

// LDS layout (bytes):
//   w_s    : 64 x WSTR ushort = 99328
//   act_s  : 8 x ASTR float   = 24704   @ 99328
//   bias_s : 64 float         = 256     @ 124032
//   gate_s : 64 x 9 float     = 2304    @ 124288
#define SMEM_BYTES 126592

__device__ __forceinline__ float sigmoid_f(float v) {
    return 1.0f / (1.0f + __expf(-v));
}
__device__ __forceinline__ float tanh_f(float v) {
    float a = fabsf(v);
    float e = __expf(-2.0f * a);          // in (0,1], no overflow
    float r = (1.0f - e) / (1.0f + e);
    return v >= 0.0f ? r : -r;
}

__global__ void __launch_bounds__(256, 1) lstm_persistent(
    const float* __restrict__ x,      // [64][1024][256]
    const float* __restrict__ w_ih,   // [2048][256]
    const float* __restrict__ w_hh,   // [2048][512]
    const float* __restrict__ b_ih,   // [2048]
    const float* __restrict__ b_hh,   // [2048]
    float* __restrict__ out,          // [64][1024][512] + h_n[64][512] + c_n[64][512]
    float* __restrict__ h_buf,        // [2][64][512] in ws
    unsigned int* __restrict__ flags) // [8][32] in ws, zeroed before launch
{
    const int tid = threadIdx.x;
    const int wg  = blockIdx.x;   // 0..255
    const int bg  = wg >> 5;      // batch group 0..7
    const int hg  = wg & 31;      // hidden group 0..31

    extern __shared__ char smem[];
    unsigned short* w_s  = (unsigned short*)smem;            // [64][WSTR]
    float* act_s  = (float*)(smem + 99328);                  // [8][ASTR]
    float* bias_s = (float*)(smem + 124032);                 // [64]
    float* gate_s = (float*)(smem + 124288);                 // [64][9]

    // ---- one-time: load + pack weights (bf16, RNE) ----
    // local row r: gate = r>>4 (i,f,g,o), hl = r&15 ; global row = gate*512 + hg*16 + hl
    for (int idx = tid; idx < 64 * KDIM; idx += 256) {
        int r = idx / KDIM;
        int k = idx - r * KDIM;
        int gr = (r >> 4) * 512 + hg * 16 + (r & 15);
        float v = (k < IDIM) ? w_ih[(size_t)gr * IDIM + k]
                             : w_hh[(size_t)gr * HDIM + (k - IDIM)];
        unsigned int u = __float_as_uint(v);
        unsigned int bf = (u + 0x7fffu + ((u >> 16) & 1u)) >> 16;  // RNE
        w_s[r * WSTR + k] = (unsigned short)bf;
    }
    if (tid < 64) {
        int gr = (tid >> 4) * 512 + hg * 16 + (tid & 15);
        bias_s[tid] = b_ih[gr] + b_hh[gr];
    }
    __syncthreads();

    // matmul thread mapping: wave w -> rows 16w..16w+15 ; within wave:
    //   row = 16w + (lane&15), bq = lane>>4 -> batches {2bq, 2bq+1}
    const int wv   = tid >> 6;
    const int lane = tid & 63;
    const int row  = wv * 16 + (lane & 15);
    const int bq   = lane >> 4;
    const int b0   = 2 * bq, b1 = 2 * bq + 1;

    // cell state for activation threads (tid<128): bl = tid>>4, hl = tid&15
    float creg = 0.0f, hreg = 0.0f;

    for (int t = 0; t < TSTEPS; ++t) {
        // ---- stage x_t (independent of h, do before waiting) ----
        {
            int bl = tid >> 5;               // 0..7
            int k0 = (tid & 31) * 8;         // 0..248
            const float* xp = x + (((size_t)(bg * 8 + bl)) * TSTEPS + t) * IDIM + k0;
            float4 v0 = *(const float4*)xp;
            float4 v1 = *(const float4*)(xp + 4);
            float* ap = act_s + bl * ASTR + k0;
            *(float4*)ap       = v0;
            *(float4*)(ap + 4) = v1;
        }

        // ---- wait for h_t, stage it ----
        if (t > 0) {
            if (tid < 32) {
                const unsigned int tgt = (unsigned int)t;
                while (__hip_atomic_load(&flags[bg * 32 + tid], __ATOMIC_ACQUIRE,
                                         __HIP_MEMORY_SCOPE_AGENT) < tgt) {
                    __builtin_amdgcn_s_sleep(1);
                }
            }
            __syncthreads();   // h_buf visible to whole WG
            int bl = tid >> 5;
            int k0 = (tid & 31) * 16;
            const float* hp = h_buf + ((size_t)(t & 1) * NBATCH + bg * 8 + bl) * HDIM + k0;
            float4 v0 = *(const float4*)(hp);
            float4 v1 = *(const float4*)(hp + 4);
            float4 v2 = *(const float4*)(hp + 8);
            float4 v3 = *(const float4*)(hp + 12);
            float* ap = act_s + bl * ASTR + IDIM + k0;
            *(float4*)(ap)      = v0;
            *(float4*)(ap + 4)  = v1;
            *(float4*)(ap + 8)  = v2;
            *(float4*)(ap + 12) = v3;
        } else {
            int bl = tid >> 5;
            int k0 = (tid & 31) * 16;
            float* ap = act_s + bl * ASTR + IDIM + k0;
            float4 z = make_float4(0.f, 0.f, 0.f, 0.f);
            *(float4*)(ap)      = z;
            *(float4*)(ap + 4)  = z;
            *(float4*)(ap + 8)  = z;
            *(float4*)(ap + 12) = z;
        }
        __syncthreads();   // act_s fully staged

        // ---- matmul: 64 rows x 8 batches, K=768 ----
        {
            float acc0 = 0.0f, acc1 = 0.0f;
            const unsigned short* wp = w_s + row * WSTR;
            const float* a0p = act_s + b0 * ASTR;
            const float* a1p = act_s + b1 * ASTR;
            #pragma unroll 2
            for (int k = 0; k < KDIM; k += 8) {
                uint4 wv4 = *(const uint4*)(wp + k);
                float4 a00 = *(const float4*)(a0p + k);
                float4 a01 = *(const float4*)(a0p + k + 4);
                float4 a10 = *(const float4*)(a1p + k);
                float4 a11 = *(const float4*)(a1p + k + 4);
                float w0 = __uint_as_float(wv4.x << 16);
                float w1 = __uint_as_float(wv4.x & 0xffff0000u);
                float w2 = __uint_as_float(wv4.y << 16);
                float w3 = __uint_as_float(wv4.y & 0xffff0000u);
                float w4 = __uint_as_float(wv4.z << 16);
                float w5 = __uint_as_float(wv4.z & 0xffff0000u);
                float w6 = __uint_as_float(wv4.w << 16);
                float w7 = __uint_as_float(wv4.w & 0xffff0000u);
                acc0 = fmaf(w0, a00.x, acc0); acc0 = fmaf(w1, a00.y, acc0);
                acc0 = fmaf(w2, a00.z, acc0); acc0 = fmaf(w3, a00.w, acc0);
                acc0 = fmaf(w4, a01.x, acc0); acc0 = fmaf(w5, a01.y, acc0);
                acc0 = fmaf(w6, a01.z, acc0); acc0 = fmaf(w7, a01.w, acc0);
                acc1 = fmaf(w0, a10.x, acc1); acc1 = fmaf(w1, a10.y, acc1);
                acc1 = fmaf(w2, a10.z, acc1); acc1 = fmaf(w3, a10.w, acc1);
                acc1 = fmaf(w4, a11.x, acc1); acc1 = fmaf(w5, a11.y, acc1);
                acc1 = fmaf(w6, a11.z, acc1); acc1 = fmaf(w7, a11.w, acc1);
            }
            gate_s[row * 9 + b0] = acc0;
            gate_s[row * 9 + b1] = acc1;
        }
        __syncthreads();   // gates ready

        // ---- activations + state update (tid<128: one (batch,hidden) pair) ----
        if (tid < 128) {
            int bl = tid >> 4;    // 0..7
            int hl = tid & 15;    // 0..15
            float gi = gate_s[(     hl) * 9 + bl] + bias_s[     hl];
            float gf = gate_s[(16 + hl) * 9 + bl] + bias_s[16 + hl];
            float gg = gate_s[(32 + hl) * 9 + bl] + bias_s[32 + hl];
            float go = gate_s[(48 + hl) * 9 + bl] + bias_s[48 + hl];
            float ig = sigmoid_f(gi);
            float fg = sigmoid_f(gf);
            float gt = tanh_f(gg);
            float og = sigmoid_f(go);
            creg = fg * creg + ig * gt;
            float hn = og * tanh_f(creg);
            hreg = hn;
            int gb = bg * 8 + bl;
            int gh = hg * 16 + hl;
            h_buf[((size_t)((t + 1) & 1) * NBATCH + gb) * HDIM + gh] = hn;
            out[((size_t)gb * TSTEPS + t) * HDIM + gh] = hn;
        }
        __syncthreads();   // all h_buf/out stores issued & complete (barrier drains vm)

        // ---- publish h_{t+1} ----
        if (tid == 0) {
            __threadfence();   // device-scope: push WG's stores to coherence point
            __hip_atomic_store(&flags[bg * 32 + hg], (unsigned int)(t + 1),
                               __ATOMIC_RELAXED, __HIP_MEMORY_SCOPE_AGENT);
        }
    }

    // ---- h_n, c_n ----
    if (tid < 128) {
        int bl = tid >> 4;
        int hl = tid & 15;
        int gb = bg * 8 + bl;
        int gh = hg * 16 + hl;
        const size_t HN_OFF = (size_t)NBATCH * TSTEPS * HDIM;            // 33554432
        const size_t CN_OFF = HN_OFF + (size_t)NBATCH * HDIM;            // +32768
        out[HN_OFF + (size_t)gb * HDIM + gh] = hreg;
        out[CN_OFF + (size_t)gb * HDIM + gh] = creg;
    }
}

extern "C" void kernel_launch(void* const* d_in, const int* in_sizes, int n_in,
                              void* d_out, int out_size, void* d_ws, size_t ws_size,
                              hipStream_t stream) {
    const float* x    = (const float*)d_in[0];
    const float* w_ih = (const float*)d_in[1];
    const float* w_hh = (const float*)d_in[2];
    const float* b_ih = (const float*)d_in[3];
    const float* b_hh = (const float*)d_in[4];
    float* out = (float*)d_out;

    // ws layout: [0,4096) flags (zeroed), [4096, 4096+256KB) h double-buffer
    unsigned int* flags = (unsigned int*)d_ws;
    float* h_buf = (float*)((char*)d_ws + 4096);

    hipMemsetAsync(d_ws, 0, 4096, stream);

    hipFuncSetAttribute((const void*)lstm_persistent,
                        hipFuncAttributeMaxDynamicSharedMemorySize, SMEM_BYTES);

    void* args[] = {(void*)&x, (void*)&w_ih, (void*)&w_hh, (void*)&b_ih,
                    (void*)&b_hh, (void*)&out, (void*)&h_buf, (void*)&flags};
    hipError_t err = hipLaunchCooperativeKernel((void*)lstm_persistent,
                                                dim3(256), dim3(256), args,
                                                SMEM_BYTES, stream);
    if (err != hipSuccess) {
        // 256 blocks x 1 WG/CU on 256 CUs are co-resident in practice
        hipLaunchKernelGGL(lstm_persistent, dim3(256), dim3(256), SMEM_BYTES,
                           stream, x, w_ih, w_hh, b_ih, b_hh, out, h_buf, flags);
    }
}

// Round 2
// 8281.835 us; speedup vs baseline: 2.3896x; 2.3896x over previous
//
#include <hip/hip_runtime.h>
#include <cstdint>
#include <cstddef>

// LSTM B=64,T=1024,I=256,H=512. Persistent kernel, 256 WGs = 4 bg x 64 hg.
// WG (bg,hg): batches bg*16..+15, hidden hg*8..+7 -> 32 gate rows, K=768.
// Matmul: mfma_f32_16x16x32_bf16, 4 waves = 2 M-tiles x 2 K-halves.
// h exchange: bf16 via agent-scope relaxed atomics (write-through to LLC,
// no cache invalidates/writebacks). Flags: monotone per-(bg,hg) counters.

#define NBATCH 64
#define TSTEPS 1024
#define IDIM   256
#define HDIM   512
#define KDIM   768
#define WS     776          // ushort k-stride (odd # of 16B slots -> uniform banks)
#define PS     17           // partial-gate fp32 col stride

#define W_OFF    0          // 32 x WS ushort  = 49664 B
#define A_OFF    49664      // 16 x WS ushort  = 24832 B
#define P_OFF    74496      // 2 x 32 x PS fp32 = 4352 B
#define BIAS_OFF 78848      // 32 fp32
#define SMEM_BYTES 78976

typedef __attribute__((ext_vector_type(8))) short short8x;   // 8 bf16
typedef __attribute__((ext_vector_type(4))) float f32x4;

__device__ __forceinline__ float sigmoid_f(float v) {
    return 1.0f / (1.0f + __expf(-v));
}
__device__ __forceinline__ float tanh_f(float v) {
    float a = fabsf(v);
    float e = __expf(-2.0f * a);
    float r = (1.0f - e) / (1.0f + e);
    return v >= 0.0f ? r : -r;
}
__device__ __forceinline__ unsigned short f2bf(float f) {
    unsigned int u = __float_as_uint(f);
    return (unsigned short)((u + 0x7fffu + ((u >> 16) & 1u)) >> 16);  // RNE
}
__device__ __forceinline__ unsigned long long pack4(float4 v) {
    unsigned long long b0 = f2bf(v.x), b1 = f2bf(v.y), b2 = f2bf(v.z), b3 = f2bf(v.w);
    return b0 | (b1 << 16) | (b2 << 32) | (b3 << 48);
}

__global__ void __launch_bounds__(256, 1) lstm_persistent(
    const float* __restrict__ x,      // [64][1024][256]
    const float* __restrict__ w_ih,   // [2048][256]
    const float* __restrict__ w_hh,   // [2048][512]
    const float* __restrict__ b_ih,   // [2048]
    const float* __restrict__ b_hh,   // [2048]
    float* __restrict__ out,          // [64][1024][512] + h_n + c_n
    unsigned long long* __restrict__ h_buf,  // [2][64][512] bf16 as ull (8192 ull/buf)
    unsigned int* __restrict__ flags)        // [4][64], zeroed pre-launch
{
    const int tid = threadIdx.x;
    const int wg  = blockIdx.x;
    const int bg  = wg >> 6;     // 0..3
    const int hg  = wg & 63;     // 0..63

    extern __shared__ char smem[];
    unsigned short* w_s  = (unsigned short*)(smem + W_OFF);
    unsigned short* a_s  = (unsigned short*)(smem + A_OFF);
    float* p_s    = (float*)(smem + P_OFF);
    float* bias_s = (float*)(smem + BIAS_OFF);

    // ---- one-time: weights -> LDS bf16. local row r: gate=r>>3, hl=r&7 ----
    for (int idx = tid; idx < 32 * KDIM; idx += 256) {
        int r = idx / KDIM;
        int k = idx - r * KDIM;
        int gr = (r >> 3) * HDIM + hg * 8 + (r & 7);
        float v = (k < IDIM) ? w_ih[(size_t)gr * IDIM + k]
                             : w_hh[(size_t)gr * HDIM + (k - IDIM)];
        w_s[r * WS + k] = f2bf(v);
    }
    if (tid < 32) {
        int gr = (tid >> 3) * HDIM + hg * 8 + (tid & 7);
        bias_s[tid] = b_ih[gr] + b_hh[gr];
    }

    // ---- per-thread mappings ----
    const int wv   = tid >> 6;          // wave 0..3
    const int lane = tid & 63;
    const int ln   = lane & 15;         // m (A row) / n (batch col)
    const int q    = lane >> 4;         // quad
    const int mt   = wv & 1;            // M-tile
    const int kh   = wv >> 1;           // K-half
    const unsigned short* Abase = w_s + (size_t)(mt * 16 + ln) * WS + kh * 384 + q * 8;
    const unsigned short* Bbase = a_s + (size_t)ln * WS + kh * 384 + q * 8;

    // staging: thread -> (batch sn, chunk sj)
    const int sn = tid >> 4;            // 0..15
    const int sj = tid & 15;            // 0..15
    const float* xbase = x + (size_t)(bg * 16 + sn) * TSTEPS * IDIM + sj * 16;
    unsigned short* axp = a_s + (size_t)sn * WS + sj * 16;          // x region
    unsigned short* ahp = a_s + (size_t)sn * WS + IDIM + sj * 32;   // h region

    // activation: tid<128 -> (batch bl, hidden hl)
    const int bl = tid & 15;
    const int hl = (tid >> 4) & 7;
    const int gb = bg * 16 + bl;
    const int gh = hg * 8 + hl;
    float creg = 0.0f, hreg = 0.0f;

    for (int t = 0; t < TSTEPS; ++t) {
        // ---- stage x_t (fp32 -> bf16), independent of h ----
        {
            const float* xp = xbase + (size_t)t * IDIM;
            float4 v0 = *(const float4*)(xp);
            float4 v1 = *(const float4*)(xp + 4);
            float4 v2 = *(const float4*)(xp + 8);
            float4 v3 = *(const float4*)(xp + 12);
            *(unsigned long long*)(axp + 0)  = pack4(v0);
            *(unsigned long long*)(axp + 4)  = pack4(v1);
            *(unsigned long long*)(axp + 8)  = pack4(v2);
            *(unsigned long long*)(axp + 12) = pack4(v3);
        }

        // ---- wait for h_t, stage it (bf16, straight copy) ----
        if (t > 0) {
            if (tid < 64) {
                const unsigned int tgt = (unsigned int)t;
                while (__hip_atomic_load(&flags[bg * 64 + tid], __ATOMIC_RELAXED,
                                         __HIP_MEMORY_SCOPE_AGENT) < tgt) {
                    __builtin_amdgcn_s_sleep(1);
                }
            }
            __syncthreads();
            const unsigned long long* hp =
                h_buf + (size_t)(t & 1) * 8192 + (size_t)(bg * 16 + sn) * 128 + sj * 8;
            unsigned long long hv[8];
            #pragma unroll
            for (int u = 0; u < 8; ++u)
                hv[u] = __hip_atomic_load(hp + u, __ATOMIC_RELAXED,
                                          __HIP_MEMORY_SCOPE_AGENT);
            #pragma unroll
            for (int u = 0; u < 8; ++u)
                *(unsigned long long*)(ahp + u * 4) = hv[u];
        } else {
            #pragma unroll
            for (int u = 0; u < 8; ++u)
                *(unsigned long long*)(ahp + u * 4) = 0ull;
        }
        __syncthreads();   // A: a_s (and, at t=0, w_s/bias) ready

        // ---- MFMA: [32 x 768] x [768 x 16], wave = (M-tile, K-half) ----
        {
            f32x4 acc = {0.f, 0.f, 0.f, 0.f};
            #pragma unroll
            for (int s = 0; s < 12; ++s) {
                short8x af = *(const short8x*)(Abase + s * 32);
                short8x bf = *(const short8x*)(Bbase + s * 32);
                acc = __builtin_amdgcn_mfma_f32_16x16x32_bf16(af, bf, acc, 0, 0, 0);
            }
            // D[m][n]: row = mt*16 + q*4 + r, col = ln
            float* pw = p_s + kh * (32 * PS) + (mt * 16 + q * 4) * PS + ln;
            pw[0]      = acc[0];
            pw[PS]     = acc[1];
            pw[2 * PS] = acc[2];
            pw[3 * PS] = acc[3];
        }
        __syncthreads();   // B: partials ready

        // ---- activation + state update + packed bf16 h publish ----
        unsigned long long hword = 0;
        if (tid < 128) {
            float gi = p_s[(     hl) * PS + bl] + p_s[32 * PS + (     hl) * PS + bl] + bias_s[     hl];
            float gf = p_s[( 8 + hl) * PS + bl] + p_s[32 * PS + ( 8 + hl) * PS + bl] + bias_s[ 8 + hl];
            float gg = p_s[(16 + hl) * PS + bl] + p_s[32 * PS + (16 + hl) * PS + bl] + bias_s[16 + hl];
            float go = p_s[(24 + hl) * PS + bl] + p_s[32 * PS + (24 + hl) * PS + bl] + bias_s[24 + hl];
            float ig = sigmoid_f(gi);
            float fg = sigmoid_f(gf);
            float gt = tanh_f(gg);
            float og = sigmoid_f(go);
            creg = fg * creg + ig * gt;
            float hn = og * tanh_f(creg);
            hreg = hn;
            // pack 4 hidden (hl, hl+1, hl+2, hl+3 within this wave) via shuffles
            int hb = (int)f2bf(hn);
            int h1 = __shfl_down(hb, 16);
            int h2 = __shfl_down(hb, 32);
            int h3 = __shfl_down(hb, 48);
            if (lane < 16) {
                hword = (unsigned long long)(unsigned short)hb
                      | ((unsigned long long)(unsigned short)h1 << 16)
                      | ((unsigned long long)(unsigned short)h2 << 32)
                      | ((unsigned long long)(unsigned short)h3 << 48);
                // wave 0 -> hidden 0..3, wave 1 -> hidden 4..7, batch = lane
                size_t di = (size_t)((t + 1) & 1) * 8192
                          + (size_t)(bg * 16 + lane) * 128 + hg * 2 + wv;
                __hip_atomic_store(h_buf + di, hword, __ATOMIC_RELAXED,
                                   __HIP_MEMORY_SCOPE_AGENT);
            }
        }
        __syncthreads();   // C: h stores drained (vmcnt(0) before barrier)

        if (tid == 0) {
            __hip_atomic_store(&flags[bg * 64 + hg], (unsigned int)(t + 1),
                               __ATOMIC_RELEASE, __HIP_MEMORY_SCOPE_AGENT);
        }

        // off critical path: fp32 out store
        if (tid < 128) {
            out[((size_t)gb * TSTEPS + t) * HDIM + gh] = hreg;
        }
    }

    // ---- h_n, c_n ----
    if (tid < 128) {
        const size_t HN_OFF = (size_t)NBATCH * TSTEPS * HDIM;   // 33554432
        const size_t CN_OFF = HN_OFF + (size_t)NBATCH * HDIM;   // +32768
        out[HN_OFF + (size_t)gb * HDIM + gh] = hreg;
        out[CN_OFF + (size_t)gb * HDIM + gh] = creg;
    }
}

extern "C" void kernel_launch(void* const* d_in, const int* in_sizes, int n_in,
                              void* d_out, int out_size, void* d_ws, size_t ws_size,
                              hipStream_t stream) {
    const float* x    = (const float*)d_in[0];
    const float* w_ih = (const float*)d_in[1];
    const float* w_hh = (const float*)d_in[2];
    const float* b_ih = (const float*)d_in[3];
    const float* b_hh = (const float*)d_in[4];
    float* out = (float*)d_out;

    // ws: [0,4096) flags (zeroed); [4096, 4096+128KB) bf16 h double-buffer
    unsigned int* flags = (unsigned int*)d_ws;
    unsigned long long* h_buf = (unsigned long long*)((char*)d_ws + 4096);

    hipMemsetAsync(d_ws, 0, 4096, stream);

    hipFuncSetAttribute((const void*)lstm_persistent,
                        hipFuncAttributeMaxDynamicSharedMemorySize, SMEM_BYTES);

    void* args[] = {(void*)&x, (void*)&w_ih, (void*)&w_hh, (void*)&b_ih,
                    (void*)&b_hh, (void*)&out, (void*)&h_buf, (void*)&flags};
    hipError_t err = hipLaunchCooperativeKernel((void*)lstm_persistent,
                                                dim3(256), dim3(256), args,
                                                SMEM_BYTES, stream);
    if (err != hipSuccess) {
        hipLaunchKernelGGL(lstm_persistent, dim3(256), dim3(256), SMEM_BYTES,
                           stream, x, w_ih, w_hh, b_ih, b_hh, out, h_buf, flags);
    }
}

// Round 4
// 7642.457 us; speedup vs baseline: 2.5896x; 1.0837x over previous
//
#include <hip/hip_runtime.h>
#include <cstdint>
#include <cstddef>

// LSTM B=64,T=1024,I=256,H=512. Persistent kernel, 256 WGs = 4 bg x 64 hg.
// WG (bg,hg): batches bg*16..+15, hidden hg*8..+7 -> 32 gate rows, K=768.
// Matmul: mfma_f32_16x16x32_bf16, 4 waves = 2 M-tiles x 2 K-halves.
// h exchange: TAGGED words. Each h element is a 4B word ((t)<<16 | bf16(h)),
// double-buffered [2][64][512]. Producers: one relaxed agent-scope 4B atomic
// store per (batch,hidden). Consumers poll the data words directly (tag==t)
// -- detection and payload in the same LLC round trip; no flags, no fences,
// no producer-side barrier. Overwrite safety: producer writes tag t+3 over
// tag t+1 only after consuming all of tag t+2, which transitively requires
// every WG to have finished reading tag t+1. ws poison 0xAAAA never matches
// a tag (tags are 1..1024), so no memset is needed.
// out[:, t-1, :] is written by one rotating consumer WG per bg per step
// (full contiguous lines, nontemporal) -- off everyone else's critical path.

#define NBATCH 64
#define TSTEPS 1024
#define IDIM   256
#define HDIM   512
#define KDIM   768
#define WS     776          // ushort k-stride (odd # of 16B slots -> spread banks)
#define PS     17           // partial-gate fp32 col stride

#define W_OFF    0          // 32 x WS ushort  = 49664 B
#define A_OFF    49664      // 16 x WS ushort  = 24832 B
#define P_OFF    74496      // 2 x 32 x PS fp32 = 4352 B
#define BIAS_OFF 78848      // 32 fp32 = 128 B
#define SMEM_BYTES 78976

#define HB_WORDS 32768      // words per h buffer: 64*512

typedef __attribute__((ext_vector_type(8))) short short8x;   // 8 bf16
typedef __attribute__((ext_vector_type(4))) float f32x4;

__device__ __forceinline__ float sigmoid_f(float v) {
    return 1.0f / (1.0f + __expf(-v));
}
__device__ __forceinline__ float tanh_f(float v) {
    float a = fabsf(v);
    float e = __expf(-2.0f * a);
    float r = (1.0f - e) / (1.0f + e);
    return v >= 0.0f ? r : -r;
}
__device__ __forceinline__ unsigned short f2bf(float f) {
    unsigned int u = __float_as_uint(f);
    return (unsigned short)((u + 0x7fffu + ((u >> 16) & 1u)) >> 16);  // RNE
}
__device__ __forceinline__ unsigned long long pack4(float4 v) {
    unsigned long long b0 = f2bf(v.x), b1 = f2bf(v.y), b2 = f2bf(v.z), b3 = f2bf(v.w);
    return b0 | (b1 << 16) | (b2 << 32) | (b3 << 48);
}

__global__ void __launch_bounds__(256, 1) lstm_persistent(
    const float* __restrict__ x,      // [64][1024][256]
    const float* __restrict__ w_ih,   // [2048][256]
    const float* __restrict__ w_hh,   // [2048][512]
    const float* __restrict__ b_ih,   // [2048]
    const float* __restrict__ b_hh,   // [2048]
    float* __restrict__ out,          // [64][1024][512] + h_n + c_n
    unsigned int* __restrict__ h_tb)  // tagged h: [2][64][512] uint32 in ws
{
    const int tid = threadIdx.x;
    const int wg  = blockIdx.x;
    const int bg  = wg >> 6;     // 0..3
    const int hg  = wg & 63;     // 0..63

    extern __shared__ char smem[];
    unsigned short* w_s  = (unsigned short*)(smem + W_OFF);
    unsigned short* a_s  = (unsigned short*)(smem + A_OFF);
    float* p_s    = (float*)(smem + P_OFF);
    float* bias_s = (float*)(smem + BIAS_OFF);

    // ---- one-time: weights -> LDS bf16. local row r: gate=r>>3, hl=r&7 ----
    for (int idx = tid; idx < 32 * KDIM; idx += 256) {
        int r = idx / KDIM;
        int k = idx - r * KDIM;
        int gr = (r >> 3) * HDIM + hg * 8 + (r & 7);
        float v = (k < IDIM) ? w_ih[(size_t)gr * IDIM + k]
                             : w_hh[(size_t)gr * HDIM + (k - IDIM)];
        w_s[r * WS + k] = f2bf(v);
    }
    if (tid < 32) {
        int gr = (tid >> 3) * HDIM + hg * 8 + (tid & 7);
        bias_s[tid] = b_ih[gr] + b_hh[gr];
    }

    // ---- per-thread mappings ----
    const int wv   = tid >> 6;          // wave 0..3
    const int lane = tid & 63;
    const int ln   = lane & 15;         // m (A row) / n (batch col)
    const int q    = lane >> 4;         // quad
    const int mt   = wv & 1;            // M-tile
    const int kh   = wv >> 1;           // K-half
    const unsigned short* Abase = w_s + (size_t)(mt * 16 + ln) * WS + kh * 384 + q * 8;
    const unsigned short* Bbase = a_s + (size_t)ln * WS + kh * 384 + q * 8;

    // staging / consume: thread -> (batch sn, chunk sj)
    const int sn = tid >> 4;            // 0..15 (local batch)
    const int sj = tid & 15;            // 0..15
    const int gbn = bg * 16 + sn;       // global batch for staging role
    const float* xbase = x + (size_t)gbn * TSTEPS * IDIM + sj * 16;
    unsigned short* axp = a_s + (size_t)sn * WS + sj * 16;          // x region
    unsigned short* ahp = a_s + (size_t)sn * WS + IDIM + sj * 32;   // h region

    // activation: tid<128 -> (batch bl, hidden hl)
    const int bl = tid & 15;
    const int hl = (tid >> 4) & 7;
    const int gb = bg * 16 + bl;
    const int gh = hg * 8 + hl;
    float creg = 0.0f, hreg = 0.0f;

    const unsigned long long tagmask = 0xffff0000ffff0000ull;

    for (int t = 0; t < TSTEPS; ++t) {
        // ---- stage x_t (fp32 -> bf16); drains this wave's VMEM before poll ----
        {
            const float* xp = xbase + (size_t)t * IDIM;
            float4 v0 = *(const float4*)(xp);
            float4 v1 = *(const float4*)(xp + 4);
            float4 v2 = *(const float4*)(xp + 8);
            float4 v3 = *(const float4*)(xp + 12);
            *(unsigned long long*)(axp + 0)  = pack4(v0);
            *(unsigned long long*)(axp + 4)  = pack4(v1);
            *(unsigned long long*)(axp + 8)  = pack4(v2);
            *(unsigned long long*)(axp + 12) = pack4(v3);
        }

        // ---- poll tagged h_t directly (tag == t), payload arrives with it ----
        if (t > 0) {
            const unsigned long long* hp = (const unsigned long long*)
                (h_tb + (size_t)(t & 1) * HB_WORDS + (size_t)gbn * HDIM + sj * 32);
            unsigned long long hv[16];
            const unsigned long long tagpat =
                ((unsigned long long)(unsigned)t << 48) |
                ((unsigned long long)(unsigned)t << 16);
            unsigned pend = 0xffffu;
            while (pend) {
                unsigned np = 0;
                #pragma unroll
                for (int u = 0; u < 16; ++u) {
                    if (pend & (1u << u)) {
                        hv[u] = __hip_atomic_load(hp + u, __ATOMIC_RELAXED,
                                                  __HIP_MEMORY_SCOPE_AGENT);
                    }
                }
                #pragma unroll
                for (int u = 0; u < 16; ++u) {
                    if ((pend & (1u << u)) && (hv[u] & tagmask) != tagpat)
                        np |= (1u << u);
                }
                pend = np;
            }
            // payload: low 16 bits of each 4B word -> packed bf16 pairs
            unsigned int pk[16];
            #pragma unroll
            for (int u = 0; u < 16; ++u) {
                pk[u] = (unsigned int)(hv[u] & 0xffffu)
                      | ((unsigned int)((hv[u] >> 32) & 0xffffu) << 16);
            }
            unsigned int* ahp32 = (unsigned int*)ahp;
            #pragma unroll
            for (int v = 0; v < 4; ++v) {
                uint4 w4 = make_uint4(pk[4*v], pk[4*v+1], pk[4*v+2], pk[4*v+3]);
                *(uint4*)(ahp32 + 4*v) = w4;
            }
            // rotating writer: one WG per bg writes out[:, t-1, :] (full lines)
            if (hg == ((t - 1) & 63)) {
                float* op = out + ((size_t)gbn * TSTEPS + (t - 1)) * HDIM + sj * 32;
                #pragma unroll
                for (int v = 0; v < 8; ++v) {
                    unsigned int w0 = pk[2*v], w1 = pk[2*v+1];
                    f32x4 f4;
                    f4[0] = __uint_as_float(w0 << 16);
                    f4[1] = __uint_as_float(w0 & 0xffff0000u);
                    f4[2] = __uint_as_float(w1 << 16);
                    f4[3] = __uint_as_float(w1 & 0xffff0000u);
                    __builtin_nontemporal_store(f4, (f32x4*)(op + 4*v));
                }
            }
        } else {
            unsigned int* ahp32 = (unsigned int*)ahp;
            uint4 z = make_uint4(0u, 0u, 0u, 0u);
            #pragma unroll
            for (int v = 0; v < 4; ++v) *(uint4*)(ahp32 + 4*v) = z;
        }
        __syncthreads();   // barrier A: a_s staged (t=0: also w_s/bias)

        // ---- MFMA: [32 x 768] x [768 x 16], wave = (M-tile, K-half) ----
        {
            f32x4 acc = {0.f, 0.f, 0.f, 0.f};
            #pragma unroll
            for (int s = 0; s < 12; ++s) {
                short8x af = *(const short8x*)(Abase + s * 32);
                short8x bf = *(const short8x*)(Bbase + s * 32);
                acc = __builtin_amdgcn_mfma_f32_16x16x32_bf16(af, bf, acc, 0, 0, 0);
            }
            // D[m][n]: row = mt*16 + q*4 + r, col = ln
            float* pw = p_s + kh * (32 * PS) + (mt * 16 + q * 4) * PS + ln;
            pw[0]      = acc[0];
            pw[PS]     = acc[1];
            pw[2 * PS] = acc[2];
            pw[3 * PS] = acc[3];
        }
        __syncthreads();   // barrier B: partials ready

        // ---- activation + state update + tagged publish (no barrier after) ----
        if (tid < 128) {
            float gi = p_s[(     hl) * PS + bl] + p_s[32 * PS + (     hl) * PS + bl] + bias_s[     hl];
            float gf = p_s[( 8 + hl) * PS + bl] + p_s[32 * PS + ( 8 + hl) * PS + bl] + bias_s[ 8 + hl];
            float gg = p_s[(16 + hl) * PS + bl] + p_s[32 * PS + (16 + hl) * PS + bl] + bias_s[16 + hl];
            float go = p_s[(24 + hl) * PS + bl] + p_s[32 * PS + (24 + hl) * PS + bl] + bias_s[24 + hl];
            float ig = sigmoid_f(gi);
            float fg = sigmoid_f(gf);
            float gt = tanh_f(gg);
            float og = sigmoid_f(go);
            creg = fg * creg + ig * gt;
            float hn = og * tanh_f(creg);
            hreg = hn;
            unsigned int word = ((unsigned int)(t + 1) << 16) | (unsigned int)f2bf(hn);
            __hip_atomic_store(
                h_tb + (size_t)((t + 1) & 1) * HB_WORDS + (size_t)gb * HDIM + gh,
                word, __ATOMIC_RELAXED, __HIP_MEMORY_SCOPE_AGENT);
        }
        // no barrier: a_s restage next iter doesn't conflict with p_s reads,
        // and MFMA a_s reads for step t completed before barrier B.
    }

    // ---- final row out[:,1023,:] + h_n, c_n (producers hold h_T, c_T) ----
    if (tid < 128) {
        const size_t HN_OFF = (size_t)NBATCH * TSTEPS * HDIM;   // 33554432
        const size_t CN_OFF = HN_OFF + (size_t)NBATCH * HDIM;   // +32768
        out[((size_t)gb * TSTEPS + (TSTEPS - 1)) * HDIM + gh] = hreg;
        out[HN_OFF + (size_t)gb * HDIM + gh] = hreg;
        out[CN_OFF + (size_t)gb * HDIM + gh] = creg;
    }
}

extern "C" void kernel_launch(void* const* d_in, const int* in_sizes, int n_in,
                              void* d_out, int out_size, void* d_ws, size_t ws_size,
                              hipStream_t stream) {
    const float* x    = (const float*)d_in[0];
    const float* w_ih = (const float*)d_in[1];
    const float* w_hh = (const float*)d_in[2];
    const float* b_ih = (const float*)d_in[3];
    const float* b_hh = (const float*)d_in[4];
    float* out = (float*)d_out;

    // ws: [0, 256KB) tagged h double-buffer. No zeroing needed: 0xAAAA poison
    // can never equal a live tag (tags are 1..1024).
    unsigned int* h_tb = (unsigned int*)d_ws;

    (void)hipFuncSetAttribute((const void*)lstm_persistent,
                        hipFuncAttributeMaxDynamicSharedMemorySize, SMEM_BYTES);

    void* args[] = {(void*)&x, (void*)&w_ih, (void*)&w_hh, (void*)&b_ih,
                    (void*)&b_hh, (void*)&out, (void*)&h_tb};
    hipError_t err = hipLaunchCooperativeKernel((void*)lstm_persistent,
                                                dim3(256), dim3(256), args,
                                                SMEM_BYTES, stream);
    if (err != hipSuccess) {
        hipLaunchKernelGGL(lstm_persistent, dim3(256), dim3(256), SMEM_BYTES,
                           stream, x, w_ih, w_hh, b_ih, b_hh, out, h_tb);
    }
}